// Round 2
// baseline (720.074 us; speedup 1.0000x reference)
//
#include <hip/hip_runtime.h>
#include <hip/hip_bf16.h>

typedef __bf16 bf16_t;
typedef bf16_t bf16x8 __attribute__((ext_vector_type(8)));
typedef bf16_t bf16x4 __attribute__((ext_vector_type(4)));
typedef float  f32x4  __attribute__((ext_vector_type(4)));

constexpr int BATCH = 16, S = 2048, D = 256;

// ---------------- ws layout (bytes) ----------------
// wt     : [3][256][256] bf16  (wt[w][n][k] = W_w[k][n])   @ 0        (393216)
// q      : [B][S][D] bf16                                   @ 393216   (16777216)
// k      : [B][S][D] bf16                                   @ 17170432 (16777216)
// vt     : [B][D][S] bf16  (transposed V)                   @ 33947648 (16777216)
// partial: [B*32][256] f32                                  @ 50724864 (524288)

// Kernel 1: transpose + convert weights to bf16.
__global__ void wt_kernel(const float* __restrict__ Wq, const float* __restrict__ Wk,
                          const float* __restrict__ Wv, bf16_t* __restrict__ wt) {
    int idx = blockIdx.x * 256 + threadIdx.x;
    int w = idx >> 16;
    int r = idx & 65535;
    int n = r >> 8;
    int kd = r & 255;
    const float* Wsrc = (w == 0) ? Wq : (w == 1) ? Wk : Wv;
    wt[idx] = (bf16_t)Wsrc[kd * 256 + n];
}

// Kernel 2: QKV projection GEMM. grid (512, 3), 256 threads (4 waves).
__global__ __launch_bounds__(256) void proj_kernel(
    const float* __restrict__ x, const bf16_t* __restrict__ wt,
    const float* __restrict__ bq, const float* __restrict__ bk, const float* __restrict__ bv,
    bf16_t* __restrict__ q, bf16_t* __restrict__ kmat, bf16_t* __restrict__ vt) {
    int w    = blockIdx.y;
    int wave = threadIdx.x >> 6;
    int lane = threadIdx.x & 63;
    int lm   = lane & 15;
    int lg   = lane >> 4;
    int m0   = blockIdx.x * 64 + wave * 16;

    const bf16_t* wptr = wt + w * 65536;
    const float*  bias = (w == 0) ? bq : (w == 1) ? bk : bv;

    f32x4 acc[16];
#pragma unroll
    for (int i = 0; i < 16; i++) acc[i] = f32x4{0.f, 0.f, 0.f, 0.f};

    const float* arow = x + (size_t)(m0 + lm) * D + lg * 8;
#pragma unroll
    for (int ks = 0; ks < 8; ks++) {
        float4 f0 = *(const float4*)(arow + ks * 32);
        float4 f1 = *(const float4*)(arow + ks * 32 + 4);
        bf16x8 a;
        a[0] = (bf16_t)f0.x; a[1] = (bf16_t)f0.y; a[2] = (bf16_t)f0.z; a[3] = (bf16_t)f0.w;
        a[4] = (bf16_t)f1.x; a[5] = (bf16_t)f1.y; a[6] = (bf16_t)f1.z; a[7] = (bf16_t)f1.w;
#pragma unroll
        for (int nt = 0; nt < 16; nt++) {
            bf16x8 b = *(const bf16x8*)(wptr + (nt * 16 + lm) * D + ks * 32 + lg * 8);
            acc[nt] = __builtin_amdgcn_mfma_f32_16x16x32_bf16(a, b, acc[nt], 0, 0, 0);
        }
    }

    int row0 = m0 + lg * 4;
    int bb   = row0 / S;
    int ss   = row0 % S;
#pragma unroll
    for (int nt = 0; nt < 16; nt++) {
        int col = nt * 16 + lm;
        float bval = bias[col];
        if (w == 2) {
            bf16x4 pk;
#pragma unroll
            for (int r = 0; r < 4; r++) pk[r] = (bf16_t)(acc[nt][r] + bval);
            *(bf16x4*)(vt + (size_t)bb * D * S + (size_t)col * S + ss) = pk;
        } else {
            bf16_t* dst = (w == 0) ? q : kmat;
#pragma unroll
            for (int r = 0; r < 4; r++)
                dst[(size_t)(row0 + r) * D + col] = (bf16_t)(acc[nt][r] + bval);
        }
    }
}

// Kernel 3: attention (no-max softmax: scores*1/16 are ~N(0,1.44) in log2
// domain; exp2 args stay within +-10 -> fp32-safe without running max).
// grid 512 (= B*32 q-tiles), 256 threads (4 waves), 64-key inner tile.
// Inner loop has ZERO cross-lane ops and ZERO accumulator rescales.
__global__ __launch_bounds__(256) void attn_kernel(
    const bf16_t* __restrict__ q, const bf16_t* __restrict__ kmat,
    const bf16_t* __restrict__ vt, float* __restrict__ partial) {
    __shared__ float lds_p[4][16 * 68];   // per-wave P transpose, 68-float row stride
    __shared__ float psum[4][256];

    int wave = threadIdx.x >> 6;
    int lane = threadIdx.x & 63;
    int lm   = lane & 15;
    int lg   = lane >> 4;
    int b    = blockIdx.x >> 5;
    int qt   = blockIdx.x & 31;
    int q0   = qt * 64 + wave * 16;

    const bf16_t* qbase = q + ((size_t)b * S + q0 + lm) * D + lg * 8;
    bf16x8 afrag[8];
#pragma unroll
    for (int ks = 0; ks < 8; ks++) afrag[ks] = *(const bf16x8*)(qbase + ks * 32);

    f32x4 o_acc[16];
#pragma unroll
    for (int i = 0; i < 16; i++) o_acc[i] = f32x4{0.f, 0.f, 0.f, 0.f};
    float lsum[4] = {0.f, 0.f, 0.f, 0.f};

    const bf16_t* kbb = kmat + (size_t)b * S * D;
    const bf16_t* vbb = vt + (size_t)b * D * S;
    float* myp = &lds_p[wave][0];
    constexpr float SCL = 0.0625f * 1.44269504f;

    for (int kt = 0; kt < 32; kt++) {
        // ---- Phase 1: S_tile[16 q][64 keys] ----
        f32x4 sacc[4];
#pragma unroll
        for (int nt = 0; nt < 4; nt++) sacc[nt] = f32x4{0.f, 0.f, 0.f, 0.f};
#pragma unroll
        for (int ks = 0; ks < 8; ks++) {
#pragma unroll
            for (int nt = 0; nt < 4; nt++) {
                bf16x8 bfr = *(const bf16x8*)(kbb + (size_t)(kt * 64 + nt * 16 + lm) * D + ks * 32 + lg * 8);
                sacc[nt] = __builtin_amdgcn_mfma_f32_16x16x32_bf16(afrag[ks], bfr, sacc[nt], 0, 0, 0);
            }
        }
        // ---- Phase 2: exp2, in-lane l accumulation, LDS transpose write ----
#pragma unroll
        for (int nt = 0; nt < 4; nt++) {
#pragma unroll
            for (int r = 0; r < 4; r++) {
                float p = exp2f(sacc[nt][r] * SCL);
                lsum[r] += p;
                myp[(lg * 4 + r) * 68 + nt * 16 + lm] = p;
            }
        }
        asm volatile("s_waitcnt lgkmcnt(0)" ::: "memory");
        // Read back in A layout (two k-halves of 32), convert to bf16.
        bf16x8 pfrag[2];
#pragma unroll
        for (int kf = 0; kf < 2; kf++) {
            const float* src = &myp[lm * 68 + kf * 32 + lg * 8];
            float4 h0 = *(const float4*)(src);
            float4 h1 = *(const float4*)(src + 4);
            pfrag[kf][0] = (bf16_t)h0.x; pfrag[kf][1] = (bf16_t)h0.y;
            pfrag[kf][2] = (bf16_t)h0.z; pfrag[kf][3] = (bf16_t)h0.w;
            pfrag[kf][4] = (bf16_t)h1.x; pfrag[kf][5] = (bf16_t)h1.y;
            pfrag[kf][6] = (bf16_t)h1.z; pfrag[kf][7] = (bf16_t)h1.w;
        }
        // ---- Phase 3: O += P . V ----
#pragma unroll
        for (int nt = 0; nt < 16; nt++) {
#pragma unroll
            for (int kf = 0; kf < 2; kf++) {
                bf16x8 bfr = *(const bf16x8*)(vbb + (size_t)(nt * 16 + lm) * S + kt * 64 + kf * 32 + lg * 8);
                o_acc[nt] = __builtin_amdgcn_mfma_f32_16x16x32_bf16(pfrag[kf], bfr, o_acc[nt], 0, 0, 0);
            }
        }
    }

    // ---- Epilogue: one cross-lane l reduction, then O/l summed over q ----
    float l_run[4];
#pragma unroll
    for (int r = 0; r < 4; r++) {
        float s = lsum[r];
        s += __shfl_xor(s, 1);
        s += __shfl_xor(s, 2);
        s += __shfl_xor(s, 4);
        s += __shfl_xor(s, 8);
        l_run[r] = s;
    }
#pragma unroll
    for (int nt = 0; nt < 16; nt++) {
        float t = 0.f;
#pragma unroll
        for (int r = 0; r < 4; r++) t += o_acc[nt][r] / l_run[r];
        t += __shfl_xor(t, 16);
        t += __shfl_xor(t, 32);
        if (lane < 16) psum[wave][nt * 16 + lm] = t;
    }
    __syncthreads();
    int tid = threadIdx.x;
    float tot = psum[0][tid] + psum[1][tid] + psum[2][tid] + psum[3][tid];
    partial[(size_t)blockIdx.x * 256 + tid] = tot;
}

// Kernel 4: reduce 32 q-tile partials per (b,d).
__global__ void reduce_kernel(const float* __restrict__ partial, float* __restrict__ out) {
    int b = blockIdx.x, d = threadIdx.x;
    float t = 0.f;
#pragma unroll
    for (int qt = 0; qt < 32; qt++) t += partial[(size_t)(b * 32 + qt) * 256 + d];
    out[b * 256 + d] = t;
}

extern "C" void kernel_launch(void* const* d_in, const int* in_sizes, int n_in,
                              void* d_out, int out_size, void* d_ws, size_t ws_size,
                              hipStream_t stream) {
    const float* x  = (const float*)d_in[0];
    const float* Wq = (const float*)d_in[1];
    const float* bq = (const float*)d_in[2];
    const float* Wk = (const float*)d_in[3];
    const float* bk = (const float*)d_in[4];
    const float* Wv = (const float*)d_in[5];
    const float* bv = (const float*)d_in[6];
    float* out = (float*)d_out;

    char* ws = (char*)d_ws;
    bf16_t* wt      = (bf16_t*)(ws);
    bf16_t* q       = (bf16_t*)(ws + 393216);
    bf16_t* kmat    = (bf16_t*)(ws + 17170432);
    bf16_t* vt      = (bf16_t*)(ws + 33947648);
    float*  partial = (float*) (ws + 50724864);

    wt_kernel<<<dim3(768), dim3(256), 0, stream>>>(Wq, Wk, Wv, wt);
    proj_kernel<<<dim3(512, 3), dim3(256), 0, stream>>>(x, wt, bq, bk, bv, q, kmat, vt);
    attn_kernel<<<dim3(512), dim3(256), 0, stream>>>(q, kmat, vt, partial);
    reduce_kernel<<<dim3(16), dim3(256), 0, stream>>>(partial, out);
}

// Round 3
// 694.777 us; speedup vs baseline: 1.0364x; 1.0364x over previous
//
#include <hip/hip_runtime.h>
#include <hip/hip_bf16.h>

typedef __bf16 bf16_t;
typedef bf16_t bf16x8 __attribute__((ext_vector_type(8)));
typedef bf16_t bf16x4 __attribute__((ext_vector_type(4)));
typedef float  f32x4  __attribute__((ext_vector_type(4)));

constexpr int BATCH = 16, S = 2048, D = 256;

// ---------------- ws layout (bytes) ----------------
// wt     : [3][256][256] bf16                               @ 0        (393216)
// q      : [B][S][D] bf16                                   @ 393216   (16777216)
// k      : [B][S][D] bf16                                   @ 17170432 (16777216)
// vt     : [B][D][S] bf16  (transposed V)                   @ 33947648 (16777216)
// partial: [2048][256] f32                                  @ 50724864 (2097152)

__device__ __forceinline__ float fast_exp2(float x) {
    return __builtin_amdgcn_exp2f(x);
}

// Kernel 1: transpose + convert weights to bf16.
__global__ void wt_kernel(const float* __restrict__ Wq, const float* __restrict__ Wk,
                          const float* __restrict__ Wv, bf16_t* __restrict__ wt) {
    int idx = blockIdx.x * 256 + threadIdx.x;
    int w = idx >> 16;
    int r = idx & 65535;
    int n = r >> 8;
    int kd = r & 255;
    const float* Wsrc = (w == 0) ? Wq : (w == 1) ? Wk : Wv;
    wt[idx] = (bf16_t)Wsrc[kd * 256 + n];
}

// Kernel 2: QKV projection GEMM. grid (512, 3), 256 threads (4 waves).
__global__ __launch_bounds__(256) void proj_kernel(
    const float* __restrict__ x, const bf16_t* __restrict__ wt,
    const float* __restrict__ bq, const float* __restrict__ bk, const float* __restrict__ bv,
    bf16_t* __restrict__ q, bf16_t* __restrict__ kmat, bf16_t* __restrict__ vt) {
    int w    = blockIdx.y;
    int wave = threadIdx.x >> 6;
    int lane = threadIdx.x & 63;
    int lm   = lane & 15;
    int lg   = lane >> 4;
    int m0   = blockIdx.x * 64 + wave * 16;

    const bf16_t* wptr = wt + w * 65536;
    const float*  bias = (w == 0) ? bq : (w == 1) ? bk : bv;

    f32x4 acc[16];
#pragma unroll
    for (int i = 0; i < 16; i++) acc[i] = f32x4{0.f, 0.f, 0.f, 0.f};

    const float* arow = x + (size_t)(m0 + lm) * D + lg * 8;
#pragma unroll
    for (int ks = 0; ks < 8; ks++) {
        float4 f0 = *(const float4*)(arow + ks * 32);
        float4 f1 = *(const float4*)(arow + ks * 32 + 4);
        bf16x8 a;
        a[0] = (bf16_t)f0.x; a[1] = (bf16_t)f0.y; a[2] = (bf16_t)f0.z; a[3] = (bf16_t)f0.w;
        a[4] = (bf16_t)f1.x; a[5] = (bf16_t)f1.y; a[6] = (bf16_t)f1.z; a[7] = (bf16_t)f1.w;
#pragma unroll
        for (int nt = 0; nt < 16; nt++) {
            bf16x8 b = *(const bf16x8*)(wptr + (nt * 16 + lm) * D + ks * 32 + lg * 8);
            acc[nt] = __builtin_amdgcn_mfma_f32_16x16x32_bf16(a, b, acc[nt], 0, 0, 0);
        }
    }

    int row0 = m0 + lg * 4;
    int bb   = row0 / S;
    int ss   = row0 % S;
#pragma unroll
    for (int nt = 0; nt < 16; nt++) {
        int col = nt * 16 + lm;
        float bval = bias[col];
        if (w == 2) {
            bf16x4 pk;
#pragma unroll
            for (int r = 0; r < 4; r++) pk[r] = (bf16_t)(acc[nt][r] + bval);
            *(bf16x4*)(vt + (size_t)bb * D * S + (size_t)col * S + ss) = pk;
        } else {
            bf16_t* dst = (w == 0) ? q : kmat;
#pragma unroll
            for (int r = 0; r < 4; r++)
                dst[(size_t)(row0 + r) * D + col] = (bf16_t)(acc[nt][r] + bval);
        }
    }
}

// Kernel 3: attention. Key-split design: grid 2048 blocks (16 B x 128 q-tiles
// of 16 rows). The 4 waves of a block each process an independent 512-key
// chunk of the SAME 16 q rows (no-max softmax => O and l are plain key-sums,
// so wave partials just add). Epilogue combines l via tiny LDS buffer and O
// via the per-column psum reduction.
__global__ __launch_bounds__(256, 4) void attn_kernel(
    const bf16_t* __restrict__ q, const bf16_t* __restrict__ kmat,
    const bf16_t* __restrict__ vt, float* __restrict__ partial) {
    __shared__ float lds_p[4][16 * 68];   // per-wave P transpose
    __shared__ float psum[4][256];
    __shared__ float lbuf[4][16];

    int wave = threadIdx.x >> 6;
    int lane = threadIdx.x & 63;
    int lm   = lane & 15;
    int lg   = lane >> 4;

    // XCD-aware relabel: assumed round-robin block->XCD (i%8). Give each XCD
    // two batches so its resident working set ~= K+V of 2 batches (4MB ~ L2).
    int i   = blockIdx.x;
    int b   = ((i & 7) << 1) | ((i >> 10) & 1);
    int qt  = (i >> 3) & 127;
    int q0  = qt * 16;
    int k0  = wave * 512;                 // this wave's key chunk

    const bf16_t* qbase = q + ((size_t)b * S + q0 + lm) * D + lg * 8;
    bf16x8 afrag[8];
#pragma unroll
    for (int ks = 0; ks < 8; ks++) afrag[ks] = *(const bf16x8*)(qbase + ks * 32);

    f32x4 o_acc[16];
#pragma unroll
    for (int i2 = 0; i2 < 16; i2++) o_acc[i2] = f32x4{0.f, 0.f, 0.f, 0.f};
    float lsum[4] = {0.f, 0.f, 0.f, 0.f};

    const bf16_t* kbb = kmat + (size_t)b * S * D;
    const bf16_t* vbb = vt + (size_t)b * D * S;
    float* myp = &lds_p[wave][0];
    constexpr float SCL = 0.0625f * 1.44269504f;

    for (int kt = 0; kt < 8; kt++) {
        int kidx = k0 + kt * 64;
        // ---- Phase 1: S_tile[16 q][64 keys] ----
        f32x4 sacc[4];
#pragma unroll
        for (int nt = 0; nt < 4; nt++) sacc[nt] = f32x4{0.f, 0.f, 0.f, 0.f};
#pragma unroll
        for (int ks = 0; ks < 8; ks++) {
#pragma unroll
            for (int nt = 0; nt < 4; nt++) {
                bf16x8 bfr = *(const bf16x8*)(kbb + (size_t)(kidx + nt * 16 + lm) * D + ks * 32 + lg * 8);
                sacc[nt] = __builtin_amdgcn_mfma_f32_16x16x32_bf16(afrag[ks], bfr, sacc[nt], 0, 0, 0);
            }
        }
        // ---- Phase 2: exp2, in-lane l accumulation, LDS transpose ----
#pragma unroll
        for (int nt = 0; nt < 4; nt++) {
#pragma unroll
            for (int r = 0; r < 4; r++) {
                float p = fast_exp2(sacc[nt][r] * SCL);
                lsum[r] += p;
                myp[(lg * 4 + r) * 68 + nt * 16 + lm] = p;
            }
        }
        asm volatile("s_waitcnt lgkmcnt(0)" ::: "memory");
        bf16x8 pfrag[2];
#pragma unroll
        for (int kf = 0; kf < 2; kf++) {
            const float* src = &myp[lm * 68 + kf * 32 + lg * 8];
            float4 h0 = *(const float4*)(src);
            float4 h1 = *(const float4*)(src + 4);
            pfrag[kf][0] = (bf16_t)h0.x; pfrag[kf][1] = (bf16_t)h0.y;
            pfrag[kf][2] = (bf16_t)h0.z; pfrag[kf][3] = (bf16_t)h0.w;
            pfrag[kf][4] = (bf16_t)h1.x; pfrag[kf][5] = (bf16_t)h1.y;
            pfrag[kf][6] = (bf16_t)h1.z; pfrag[kf][7] = (bf16_t)h1.w;
        }
        // ---- Phase 3: O += P . V ----
#pragma unroll
        for (int nt = 0; nt < 16; nt++) {
#pragma unroll
            for (int kf = 0; kf < 2; kf++) {
                bf16x8 bfr = *(const bf16x8*)(vbb + (size_t)(nt * 16 + lm) * S + kidx + kf * 32 + lg * 8);
                o_acc[nt] = __builtin_amdgcn_mfma_f32_16x16x32_bf16(pfrag[kf], bfr, o_acc[nt], 0, 0, 0);
            }
        }
    }

    // ---- Epilogue ----
    // 1) per-wave row-l (reduce over lm), stash in LDS
    float lpart[4];
#pragma unroll
    for (int r = 0; r < 4; r++) {
        float s = lsum[r];
        s += __shfl_xor(s, 1);
        s += __shfl_xor(s, 2);
        s += __shfl_xor(s, 4);
        s += __shfl_xor(s, 8);
        lpart[r] = s;
    }
    if (lm == 0) {
#pragma unroll
        for (int r = 0; r < 4; r++) lbuf[wave][lg * 4 + r] = lpart[r];
    }
    __syncthreads();
    // 2) full-row l and reciprocal
    float rinv[4];
#pragma unroll
    for (int r = 0; r < 4; r++) {
        int row = lg * 4 + r;
        float l = lbuf[0][row] + lbuf[1][row] + lbuf[2][row] + lbuf[3][row];
        rinv[r] = 1.0f / l;
    }
    // 3) per-column contribution of this wave: sum over its 4 C-rows of O/l
#pragma unroll
    for (int nt = 0; nt < 16; nt++) {
        float t = 0.f;
#pragma unroll
        for (int r = 0; r < 4; r++) t += o_acc[nt][r] * rinv[r];
        t += __shfl_xor(t, 16);
        t += __shfl_xor(t, 32);
        if (lane < 16) psum[wave][nt * 16 + lm] = t;
    }
    __syncthreads();
    int tid = threadIdx.x;
    float tot = psum[0][tid] + psum[1][tid] + psum[2][tid] + psum[3][tid];
    partial[((size_t)(b * 128 + qt)) * 256 + tid] = tot;
}

// Kernel 4: reduce 128 q-tile partials per (b,d).
__global__ void reduce_kernel(const float* __restrict__ partial, float* __restrict__ out) {
    int b = blockIdx.x, d = threadIdx.x;
    float t = 0.f;
    for (int qt = 0; qt < 128; qt++) t += partial[(size_t)(b * 128 + qt) * 256 + d];
    out[b * 256 + d] = t;
}

extern "C" void kernel_launch(void* const* d_in, const int* in_sizes, int n_in,
                              void* d_out, int out_size, void* d_ws, size_t ws_size,
                              hipStream_t stream) {
    const float* x  = (const float*)d_in[0];
    const float* Wq = (const float*)d_in[1];
    const float* bq = (const float*)d_in[2];
    const float* Wk = (const float*)d_in[3];
    const float* bk = (const float*)d_in[4];
    const float* Wv = (const float*)d_in[5];
    const float* bv = (const float*)d_in[6];
    float* out = (float*)d_out;

    char* ws = (char*)d_ws;
    bf16_t* wt      = (bf16_t*)(ws);
    bf16_t* q       = (bf16_t*)(ws + 393216);
    bf16_t* kmat    = (bf16_t*)(ws + 17170432);
    bf16_t* vt      = (bf16_t*)(ws + 33947648);
    float*  partial = (float*) (ws + 50724864);

    wt_kernel<<<dim3(768), dim3(256), 0, stream>>>(Wq, Wk, Wv, wt);
    proj_kernel<<<dim3(512, 3), dim3(256), 0, stream>>>(x, wt, bq, bk, bv, q, kmat, vt);
    attn_kernel<<<dim3(2048), dim3(256), 0, stream>>>(q, kmat, vt, partial);
    reduce_kernel<<<dim3(16), dim3(256), 0, stream>>>(partial, out);
}

// Round 4
// 500.103 us; speedup vs baseline: 1.4399x; 1.3893x over previous
//
#include <hip/hip_runtime.h>
#include <hip/hip_bf16.h>

typedef __bf16 bf16_t;
typedef bf16_t bf16x8 __attribute__((ext_vector_type(8)));
typedef float  f32x4  __attribute__((ext_vector_type(4)));

constexpr int BATCH = 16, S = 2048, D = 256;

// ---------------- ws layout (bytes) ----------------
// wt     : [3][256][256] bf16                               @ 0        (393216)
// q      : frag layout [B][128 qb][8 ks][64 lane][8] bf16   @ 393216   (16777216)
// k      : frag layout [B][128 kb][8 ks][64 lane][8] bf16   @ 17170432 (16777216)
// vt     : frag layout [B][16 dt][64 kc][64 lane][8] bf16   @ 33947648 (16777216)
// partial: [2048][256] f32                                  @ 50724864 (2097152)
//
// Fragment addressing (MFMA 16x16x32, lane = lg*16+lm):
//  Q/K element (row m, d): qb=m/16, lm=m%16, ks=d/32, lg=(d%32)/8, j=d%8
//    -> ((b*128+qb)*8+ks)*512 + (lg*16+lm)*8 + j
//  V^T element (d, key):  dt=d/16, lm=d%16, kc=key/32, lg=(key%32)/8, j=key%8
//    -> ((b*16+dt)*64+kc)*512 + (lg*16+lm)*8 + j
// => every attn fragment load is base + lane*16B : one contiguous 1KB burst.

__device__ __forceinline__ float fast_exp2(float x) {
    return __builtin_amdgcn_exp2f(x);
}

// Kernel 1: transpose + convert weights to bf16 (wt[w][n][k] = W[k][n]).
__global__ void wt_kernel(const float* __restrict__ Wq, const float* __restrict__ Wk,
                          const float* __restrict__ Wv, bf16_t* __restrict__ wt) {
    int idx = blockIdx.x * 256 + threadIdx.x;
    int w = idx >> 16;
    int r = idx & 65535;
    int n = r >> 8;
    int kd = r & 255;
    const float* Wsrc = (w == 0) ? Wq : (w == 1) ? Wk : Wv;
    wt[idx] = (bf16_t)Wsrc[kd * 256 + n];
}

// Kernel 2: QKV projection GEMM. grid (512, 3), 256 threads (4 waves).
// Epilogue writes q/k/vt directly in MFMA fragment order.
__global__ __launch_bounds__(256) void proj_kernel(
    const float* __restrict__ x, const bf16_t* __restrict__ wt,
    const float* __restrict__ bq, const float* __restrict__ bk, const float* __restrict__ bv,
    bf16_t* __restrict__ q, bf16_t* __restrict__ kmat, bf16_t* __restrict__ vt) {
    int w    = blockIdx.y;
    int wave = threadIdx.x >> 6;
    int lane = threadIdx.x & 63;
    int lm   = lane & 15;
    int lg   = lane >> 4;
    int m0   = blockIdx.x * 64 + wave * 16;

    const bf16_t* wptr = wt + w * 65536;
    const float*  bias = (w == 0) ? bq : (w == 1) ? bk : bv;

    f32x4 acc[16];
#pragma unroll
    for (int i = 0; i < 16; i++) acc[i] = f32x4{0.f, 0.f, 0.f, 0.f};

    const float* arow = x + (size_t)(m0 + lm) * D + lg * 8;
#pragma unroll
    for (int ks = 0; ks < 8; ks++) {
        float4 f0 = *(const float4*)(arow + ks * 32);
        float4 f1 = *(const float4*)(arow + ks * 32 + 4);
        bf16x8 a;
        a[0] = (bf16_t)f0.x; a[1] = (bf16_t)f0.y; a[2] = (bf16_t)f0.z; a[3] = (bf16_t)f0.w;
        a[4] = (bf16_t)f1.x; a[5] = (bf16_t)f1.y; a[6] = (bf16_t)f1.z; a[7] = (bf16_t)f1.w;
#pragma unroll
        for (int nt = 0; nt < 16; nt++) {
            bf16x8 b = *(const bf16x8*)(wptr + (nt * 16 + lm) * D + ks * 32 + lg * 8);
            acc[nt] = __builtin_amdgcn_mfma_f32_16x16x32_bf16(a, b, acc[nt], 0, 0, 0);
        }
    }

    // C layout: row = m0 + lg*4 + r, col = nt*16 + lm.
    int bb  = m0 / S;
    int mm0 = (m0 % S) + lg * 4;       // within-batch row for r=0
    if (w == 2) {
        // V^T fragment store: element (d=col, key=mm0+r)
#pragma unroll
        for (int nt = 0; nt < 16; nt++) {
            float bval = bias[nt * 16 + lm];
#pragma unroll
            for (int r = 0; r < 4; r++) {
                int key = mm0 + r;
                int kc  = key >> 5;
                int lgv = (key & 31) >> 3;
                int jv  = key & 7;
                vt[(size_t)(((bb * 16 + nt) * 64 + kc) * 512) + (lgv * 16 + lm) * 8 + jv]
                    = (bf16_t)(acc[nt][r] + bval);
            }
        }
    } else {
        bf16_t* dst = (w == 0) ? q : kmat;
        int qb = (m0 % S) >> 4;
#pragma unroll
        for (int nt = 0; nt < 16; nt++) {
            int col  = nt * 16 + lm;
            int ks_t = col >> 5;
            int lg_t = (col & 31) >> 3;
            int j_t  = col & 7;
            float bval = bias[col];
#pragma unroll
            for (int r = 0; r < 4; r++) {
                dst[(size_t)(((bb * 128 + qb) * 8 + ks_t) * 512) + (lg_t * 16 + lg * 4 + r) * 8 + j_t]
                    = (bf16_t)(acc[nt][r] + bval);
            }
        }
    }
}

// Kernel 3: attention, key-split. grid 2048 (16 b x 128 q-tiles), 4 waves,
// each wave owns a 512-key chunk of the same 16 q rows. All global loads are
// contiguous 1KB bursts (fragment-major layout).
__global__ __launch_bounds__(256, 3) void attn_kernel(
    const bf16_t* __restrict__ q, const bf16_t* __restrict__ kmat,
    const bf16_t* __restrict__ vt, float* __restrict__ partial) {
    __shared__ float lds_p[4][16 * 68];
    __shared__ float psum[4][256];
    __shared__ float lbuf[4][16];

    int wave = threadIdx.x >> 6;
    int lane = threadIdx.x & 63;
    int lm   = lane & 15;
    int lg   = lane >> 4;

    // XCD-aware relabel: round-robin i%8 -> XCD; give each XCD 2 batches.
    int i   = blockIdx.x;
    int b   = ((i & 7) << 1) | ((i >> 10) & 1);
    int qt  = (i >> 3) & 127;
    int k0  = wave * 512;

    const bf16_t* qf  = q    + (size_t)(b * 128 + qt) * 8 * 512;
    const bf16_t* kfb = kmat + (size_t)b * 128 * 8 * 512;
    const bf16_t* vfb = vt   + (size_t)b * 16 * 64 * 512;

    bf16x8 afrag[8];
#pragma unroll
    for (int ks = 0; ks < 8; ks++) afrag[ks] = *(const bf16x8*)(qf + ks * 512 + lane * 8);

    f32x4 o_acc[16];
#pragma unroll
    for (int i2 = 0; i2 < 16; i2++) o_acc[i2] = f32x4{0.f, 0.f, 0.f, 0.f};
    float lsum[4] = {0.f, 0.f, 0.f, 0.f};

    float* myp = &lds_p[wave][0];
    constexpr float SCL = 0.0625f * 1.44269504f;

    for (int kt = 0; kt < 8; kt++) {
        int kb0 = (k0 >> 4) + kt * 4;   // 16-key fragment blocks
        int kc0 = (k0 >> 5) + kt * 2;   // 32-key V columns
        // ---- Phase 1: S_tile[16 q][64 keys], coalesced K frag loads ----
        f32x4 sacc[4];
#pragma unroll
        for (int nt = 0; nt < 4; nt++) sacc[nt] = f32x4{0.f, 0.f, 0.f, 0.f};
#pragma unroll
        for (int ks = 0; ks < 8; ks++) {
#pragma unroll
            for (int nt = 0; nt < 4; nt++) {
                bf16x8 bfr = *(const bf16x8*)(kfb + (size_t)((kb0 + nt) * 8 + ks) * 512 + lane * 8);
                sacc[nt] = __builtin_amdgcn_mfma_f32_16x16x32_bf16(afrag[ks], bfr, sacc[nt], 0, 0, 0);
            }
        }
        // ---- Phase 2: exp2, in-lane l accumulation, LDS transpose ----
#pragma unroll
        for (int nt = 0; nt < 4; nt++) {
#pragma unroll
            for (int r = 0; r < 4; r++) {
                float p = fast_exp2(sacc[nt][r] * SCL);
                lsum[r] += p;
                myp[(lg * 4 + r) * 68 + nt * 16 + lm] = p;
            }
        }
        asm volatile("s_waitcnt lgkmcnt(0)" ::: "memory");
        bf16x8 pfrag[2];
#pragma unroll
        for (int kf = 0; kf < 2; kf++) {
            const float* src = &myp[lm * 68 + kf * 32 + lg * 8];
            float4 h0 = *(const float4*)(src);
            float4 h1 = *(const float4*)(src + 4);
            pfrag[kf][0] = (bf16_t)h0.x; pfrag[kf][1] = (bf16_t)h0.y;
            pfrag[kf][2] = (bf16_t)h0.z; pfrag[kf][3] = (bf16_t)h0.w;
            pfrag[kf][4] = (bf16_t)h1.x; pfrag[kf][5] = (bf16_t)h1.y;
            pfrag[kf][6] = (bf16_t)h1.z; pfrag[kf][7] = (bf16_t)h1.w;
        }
        // ---- Phase 3: O += P . V, coalesced V frag loads ----
#pragma unroll
        for (int nt = 0; nt < 16; nt++) {
#pragma unroll
            for (int kf = 0; kf < 2; kf++) {
                bf16x8 bfr = *(const bf16x8*)(vfb + (size_t)(nt * 64 + kc0 + kf) * 512 + lane * 8);
                o_acc[nt] = __builtin_amdgcn_mfma_f32_16x16x32_bf16(pfrag[kf], bfr, o_acc[nt], 0, 0, 0);
            }
        }
    }

    // ---- Epilogue: combine wave partials (l and O are plain key-sums) ----
    float lpart[4];
#pragma unroll
    for (int r = 0; r < 4; r++) {
        float s = lsum[r];
        s += __shfl_xor(s, 1);
        s += __shfl_xor(s, 2);
        s += __shfl_xor(s, 4);
        s += __shfl_xor(s, 8);
        lpart[r] = s;
    }
    if (lm == 0) {
#pragma unroll
        for (int r = 0; r < 4; r++) lbuf[wave][lg * 4 + r] = lpart[r];
    }
    __syncthreads();
    float rinv[4];
#pragma unroll
    for (int r = 0; r < 4; r++) {
        int row = lg * 4 + r;
        float l = lbuf[0][row] + lbuf[1][row] + lbuf[2][row] + lbuf[3][row];
        rinv[r] = 1.0f / l;
    }
#pragma unroll
    for (int nt = 0; nt < 16; nt++) {
        float t = 0.f;
#pragma unroll
        for (int r = 0; r < 4; r++) t += o_acc[nt][r] * rinv[r];
        t += __shfl_xor(t, 16);
        t += __shfl_xor(t, 32);
        if (lane < 16) psum[wave][nt * 16 + lm] = t;
    }
    __syncthreads();
    int tid = threadIdx.x;
    float tot = psum[0][tid] + psum[1][tid] + psum[2][tid] + psum[3][tid];
    partial[((size_t)(b * 128 + qt)) * 256 + tid] = tot;
}

// Kernel 4: reduce 128 q-tile partials per (b,d).
__global__ void reduce_kernel(const float* __restrict__ partial, float* __restrict__ out) {
    int b = blockIdx.x, d = threadIdx.x;
    float t = 0.f;
    for (int qt = 0; qt < 128; qt++) t += partial[(size_t)(b * 128 + qt) * 256 + d];
    out[b * 256 + d] = t;
}

extern "C" void kernel_launch(void* const* d_in, const int* in_sizes, int n_in,
                              void* d_out, int out_size, void* d_ws, size_t ws_size,
                              hipStream_t stream) {
    const float* x  = (const float*)d_in[0];
    const float* Wq = (const float*)d_in[1];
    const float* bq = (const float*)d_in[2];
    const float* Wk = (const float*)d_in[3];
    const float* bk = (const float*)d_in[4];
    const float* Wv = (const float*)d_in[5];
    const float* bv = (const float*)d_in[6];
    float* out = (float*)d_out;

    char* ws = (char*)d_ws;
    bf16_t* wt      = (bf16_t*)(ws);
    bf16_t* q       = (bf16_t*)(ws + 393216);
    bf16_t* kmat    = (bf16_t*)(ws + 17170432);
    bf16_t* vt      = (bf16_t*)(ws + 33947648);
    float*  partial = (float*) (ws + 50724864);

    wt_kernel<<<dim3(768), dim3(256), 0, stream>>>(Wq, Wk, Wv, wt);
    proj_kernel<<<dim3(512, 3), dim3(256), 0, stream>>>(x, wt, bq, bk, bv, q, kmat, vt);
    attn_kernel<<<dim3(2048), dim3(256), 0, stream>>>(q, kmat, vt, partial);
    reduce_kernel<<<dim3(16), dim3(256), 0, stream>>>(partial, out);
}

// Round 5
// 225.907 us; speedup vs baseline: 3.1875x; 2.2138x over previous
//
#include <hip/hip_runtime.h>
#include <hip/hip_bf16.h>

typedef __bf16 bf16_t;
typedef bf16_t bf16x8 __attribute__((ext_vector_type(8)));
typedef bf16_t bf16x4 __attribute__((ext_vector_type(4)));
typedef float  f32x4  __attribute__((ext_vector_type(4)));

constexpr int S = 2048, D = 256;

// ---------------- ws layout (bytes) ----------------
// wtf   : [3][16 nt][8 ks][64 lane][8] bf16 (frag-major W^T) @ 0        (393216)
// q     : frag layout [B][128 qb][8 ks][64 lane][8] bf16     @ 393216   (16777216)
// k     : frag layout [B][128 kb][8 ks][64 lane][8] bf16     @ 17170432 (16777216)
// v     : plain [B][S][D] bf16                               @ 33947648 (16777216)
// lpart : [2 kh][B][2048] f32                                @ 50724864 (262144)
// wpart : [16 qt][B][2048] f32                               @ 50987008 (2097152)
// total : 53084160 (~53.1 MB)

__device__ __forceinline__ float fast_exp2(float x) {
    return __builtin_amdgcn_exp2f(x);
}

// Kernel 1: weights -> bf16 fragment-major layout. 24576 threads.
__global__ void wt_kernel(const float* __restrict__ Wq, const float* __restrict__ Wk,
                          const float* __restrict__ Wv, bf16_t* __restrict__ wtf) {
    int idx = blockIdx.x * 256 + threadIdx.x;   // [0, 24576)
    int w    = idx >> 13;
    int rem  = idx & 8191;
    int nt   = rem >> 9;
    int rem2 = rem & 511;
    int ks   = rem2 >> 6;
    int lane = rem2 & 63;
    int lm = lane & 15, lg = lane >> 4;
    const float* Wsrc = (w == 0) ? Wq : (w == 1) ? Wk : Wv;
    int col = nt * 16 + lm, krow = ks * 32 + lg * 8;
    bf16x8 o;
#pragma unroll
    for (int j = 0; j < 8; j++) o[j] = (bf16_t)Wsrc[(krow + j) * 256 + col];
    *(bf16x8*)(wtf + (size_t)idx * 8) = o;
}

// Kernel 2: QKV projection. grid (256, 3), 256 thr. Each wave: 32 rows x 256
// cols; x staged to LDS per 32-col K-slab (dbuf, 1 barrier/slab); B-frags are
// contiguous lane*16B loads from wtf.
__global__ __launch_bounds__(256) void proj_kernel(
    const float* __restrict__ x, const bf16_t* __restrict__ wtf,
    const float* __restrict__ bq, const float* __restrict__ bk, const float* __restrict__ bv,
    bf16_t* __restrict__ qo, bf16_t* __restrict__ ko, bf16_t* __restrict__ vo) {
    __shared__ float xs[2][128 * 36];
    int w    = blockIdx.y;
    int tid  = threadIdx.x;
    int wave = tid >> 6, lane = tid & 63, lm = lane & 15, lg = lane >> 4;
    int m0   = blockIdx.x * 128;
    const bf16_t* wb   = wtf + w * 65536;
    const float*  bias = (w == 0) ? bq : (w == 1) ? bk : bv;

    f32x4 acc[2][16];
#pragma unroll
    for (int s = 0; s < 2; s++)
#pragma unroll
        for (int nt = 0; nt < 16; nt++) acc[s][nt] = f32x4{0.f, 0.f, 0.f, 0.f};

    float4 stg[4];
#pragma unroll
    for (int u = 0; u < 4; u++) {
        int f = u * 256 + tid, row = f >> 3, c4 = f & 7;
        stg[u] = *(const float4*)(x + (size_t)(m0 + row) * 256 + c4 * 4);
    }

    for (int ks = 0; ks < 8; ks++) {
        int p = ks & 1;
#pragma unroll
        for (int u = 0; u < 4; u++) {
            int f = u * 256 + tid, row = f >> 3, c4 = f & 7;
            *(float4*)&xs[p][row * 36 + c4 * 4] = stg[u];
        }
        if (ks < 7) {
#pragma unroll
            for (int u = 0; u < 4; u++) {
                int f = u * 256 + tid, row = f >> 3, c4 = f & 7;
                stg[u] = *(const float4*)(x + (size_t)(m0 + row) * 256 + (ks + 1) * 32 + c4 * 4);
            }
        }
        __syncthreads();
        bf16x8 af[2];
#pragma unroll
        for (int s = 0; s < 2; s++) {
            const float* sp = &xs[p][(wave * 32 + s * 16 + lm) * 36 + lg * 8];
            float4 h0 = *(const float4*)sp;
            float4 h1 = *(const float4*)(sp + 4);
            af[s][0] = (bf16_t)h0.x; af[s][1] = (bf16_t)h0.y;
            af[s][2] = (bf16_t)h0.z; af[s][3] = (bf16_t)h0.w;
            af[s][4] = (bf16_t)h1.x; af[s][5] = (bf16_t)h1.y;
            af[s][6] = (bf16_t)h1.z; af[s][7] = (bf16_t)h1.w;
        }
#pragma unroll
        for (int nt = 0; nt < 16; nt++) {
            bf16x8 bfr = *(const bf16x8*)(wb + (size_t)(nt * 8 + ks) * 512 + lane * 8);
            acc[0][nt] = __builtin_amdgcn_mfma_f32_16x16x32_bf16(af[0], bfr, acc[0][nt], 0, 0, 0);
            acc[1][nt] = __builtin_amdgcn_mfma_f32_16x16x32_bf16(af[1], bfr, acc[1][nt], 0, 0, 0);
        }
    }

    // Epilogue. C layout: row(set) = wave*32 + set*16 + lg*4 + r, col = nt*16+lm.
    int bglob = m0 >> 11;
    int qb0   = ((m0 & 2047) >> 4) + wave * 2;
#pragma unroll
    for (int s = 0; s < 2; s++) {
#pragma unroll
        for (int nt = 0; nt < 16; nt++) {
            int col = nt * 16 + lm;
            float bval = bias[col];
            if (w == 2) {
#pragma unroll
                for (int r = 0; r < 4; r++) {
                    int m = m0 + wave * 32 + s * 16 + lg * 4 + r;
                    int ss = m & 2047;
                    vo[((size_t)(bglob * 2048 + ss)) * 256 + col] = (bf16_t)(acc[s][nt][r] + bval);
                }
            } else {
                bf16_t* dst = (w == 0) ? qo : ko;
                int ks_t = col >> 5, lg_t = (col >> 3) & 3, j_t = col & 7;
#pragma unroll
                for (int r = 0; r < 4; r++) {
                    dst[((size_t)((bglob * 128 + qb0 + s) * 8 + ks_t)) * 512
                        + (lg_t * 16 + lg * 4 + r) * 8 + j_t] = (bf16_t)(acc[s][nt][r] + bval);
                }
            }
        }
    }
}

// Kernels 3/4: QK^T passes. grid 512 = (16 b x 16 qt(128 rows) x 2 kh(1024 keys)).
// 4 waves; wave owns 32 q-rows (2 A-frag sets in registers). K staged to LDS in
// 32-key tiles (16 KB), double-buffered, shared by all 4 waves.
// PASS=1: accumulate row-sums l -> lpart.  PASS=2: w_k = sum_q p/l -> wpart.
template <int PASS>
__global__ __launch_bounds__(256) void attn_pass(
    const bf16_t* __restrict__ q, const bf16_t* __restrict__ kmat,
    float* __restrict__ lpart, float* __restrict__ wpart) {
    __shared__ bf16_t kst[2][8192];          // 2 x 16 KB
    __shared__ float  wacc[4][1024];         // used by PASS 2

    int tid  = threadIdx.x;
    int wave = tid >> 6, lane = tid & 63, lm = lane & 15, lg = lane >> 4;
    int i  = blockIdx.x;
    int b  = ((i & 7) << 1) | ((i >> 8) & 1);   // XCD-aware: 2 batches per XCD
    int qt = (i >> 4) & 15;
    int kh = (i >> 3) & 1;

    // A-frags: 2 sets of 16 q-rows, held in registers for the whole kernel.
    bf16x8 af[2][8];
#pragma unroll
    for (int s = 0; s < 2; s++) {
        const bf16_t* qb = q + ((size_t)((b * 128 + qt * 8 + wave * 2 + s) * 8)) * 512;
#pragma unroll
        for (int ks = 0; ks < 8; ks++)
            af[s][ks] = *(const bf16x8*)(qb + ks * 512 + lane * 8);
    }

    float rinv[2][4];
    if (PASS == 2) {
#pragma unroll
        for (int s = 0; s < 2; s++)
#pragma unroll
            for (int r = 0; r < 4; r++) {
                int row = qt * 128 + wave * 32 + s * 16 + lg * 4 + r;
                float l = lpart[(size_t)b * 2048 + row] + lpart[(size_t)(16 + b) * 2048 + row];
                rinv[s][r] = 1.0f / l;
            }
    }

    float lsum[2][4];
#pragma unroll
    for (int s = 0; s < 2; s++)
#pragma unroll
        for (int r = 0; r < 4; r++) lsum[s][r] = 0.f;

    constexpr float SCL = 0.0625f * 1.44269504f;
    const bf16_t* kb_base = kmat + (size_t)(b * 128 + kh * 64) * 4096;   // elems

    bf16x8 stg[4];
#pragma unroll
    for (int u = 0; u < 4; u++)
        stg[u] = *(const bf16x8*)(kb_base + (size_t)(u * 256 + tid) * 8);

    for (int t = 0; t < 32; t++) {
        int p = t & 1;
#pragma unroll
        for (int u = 0; u < 4; u++)
            *(bf16x8*)&kst[p][(u * 256 + tid) * 8] = stg[u];
        if (t < 31) {
#pragma unroll
            for (int u = 0; u < 4; u++)
                stg[u] = *(const bf16x8*)(kb_base + (size_t)(t + 1) * 8192 + (u * 256 + tid) * 8);
        }
        __syncthreads();

        f32x4 sacc[2][2];
#pragma unroll
        for (int s = 0; s < 2; s++)
#pragma unroll
            for (int kb = 0; kb < 2; kb++) sacc[s][kb] = f32x4{0.f, 0.f, 0.f, 0.f};
#pragma unroll
        for (int ks = 0; ks < 8; ks++) {
#pragma unroll
            for (int kb = 0; kb < 2; kb++) {
                bf16x8 bfr = *(const bf16x8*)&kst[p][(kb * 8 + ks) * 512 + lane * 8];
                sacc[0][kb] = __builtin_amdgcn_mfma_f32_16x16x32_bf16(af[0][ks], bfr, sacc[0][kb], 0, 0, 0);
                sacc[1][kb] = __builtin_amdgcn_mfma_f32_16x16x32_bf16(af[1][ks], bfr, sacc[1][kb], 0, 0, 0);
            }
        }

        if (PASS == 1) {
#pragma unroll
            for (int s = 0; s < 2; s++)
#pragma unroll
                for (int kb = 0; kb < 2; kb++)
#pragma unroll
                    for (int r = 0; r < 4; r++)
                        lsum[s][r] += fast_exp2(sacc[s][kb][r] * SCL);
        } else {
            float wv[2] = {0.f, 0.f};
#pragma unroll
            for (int s = 0; s < 2; s++)
#pragma unroll
                for (int kb = 0; kb < 2; kb++)
#pragma unroll
                    for (int r = 0; r < 4; r++)
                        wv[kb] += fast_exp2(sacc[s][kb][r] * SCL) * rinv[s][r];
#pragma unroll
            for (int kb = 0; kb < 2; kb++) {
                float vsum = wv[kb];
                vsum += __shfl_xor(vsum, 16);
                vsum += __shfl_xor(vsum, 32);
                if (lg == 0) wacc[wave][t * 32 + kb * 16 + lm] = vsum;
            }
        }
    }

    if (PASS == 1) {
#pragma unroll
        for (int s = 0; s < 2; s++)
#pragma unroll
            for (int r = 0; r < 4; r++) {
                float v = lsum[s][r];
                v += __shfl_xor(v, 1);
                v += __shfl_xor(v, 2);
                v += __shfl_xor(v, 4);
                v += __shfl_xor(v, 8);
                if (lm == 0) {
                    int row = qt * 128 + wave * 32 + s * 16 + lg * 4 + r;
                    lpart[(size_t)(kh * 16 + b) * 2048 + row] = v;
                }
            }
    } else {
        __syncthreads();
        f32x4 sum = *(const f32x4*)&wacc[0][tid * 4];
#pragma unroll
        for (int w2 = 1; w2 < 4; w2++) {
            f32x4 t2 = *(const f32x4*)&wacc[w2][tid * 4];
#pragma unroll
            for (int u = 0; u < 4; u++) sum[u] += t2[u];
        }
        *(f32x4*)&wpart[(size_t)(qt * 16 + b) * 2048 + kh * 1024 + tid * 4] = sum;
    }
}

// Kernel 5: out[b,d] = sum_k w_k V[b,k,d]. grid 16 x 1024 threads.
__global__ __launch_bounds__(1024) void gemv_kernel(
    const float* __restrict__ wpart, const bf16_t* __restrict__ v, float* __restrict__ out) {
    __shared__ float ldsw[2048];
    __shared__ float psum[16][256];
    int b = blockIdx.x, tid = threadIdx.x;
#pragma unroll
    for (int u = 0; u < 2; u++) {
        int kk = u * 1024 + tid;
        float s = 0.f;
#pragma unroll
        for (int qt = 0; qt < 16; qt++) s += wpart[(size_t)(qt * 16 + b) * 2048 + kk];
        ldsw[kk] = s;
    }
    __syncthreads();
    int wave = tid >> 6, lane = tid & 63;
    const bf16_t* vb = v + (size_t)b * 2048 * 256;
    f32x4 acc = f32x4{0.f, 0.f, 0.f, 0.f};
    for (int t = 0; t < 128; t++) {
        int kk = wave * 128 + t;
        float wv = ldsw[kk];
        bf16x4 vv = *(const bf16x4*)(vb + (size_t)kk * 256 + lane * 4);
#pragma unroll
        for (int u = 0; u < 4; u++) acc[u] += wv * (float)vv[u];
    }
    *(f32x4*)&psum[wave][lane * 4] = acc;
    __syncthreads();
    if (tid < 256) {
        float s = 0.f;
#pragma unroll
        for (int w2 = 0; w2 < 16; w2++) s += psum[w2][tid];
        out[b * 256 + tid] = s;
    }
}

extern "C" void kernel_launch(void* const* d_in, const int* in_sizes, int n_in,
                              void* d_out, int out_size, void* d_ws, size_t ws_size,
                              hipStream_t stream) {
    const float* x  = (const float*)d_in[0];
    const float* Wq = (const float*)d_in[1];
    const float* bq = (const float*)d_in[2];
    const float* Wk = (const float*)d_in[3];
    const float* bk = (const float*)d_in[4];
    const float* Wv = (const float*)d_in[5];
    const float* bv = (const float*)d_in[6];
    float* out = (float*)d_out;

    char* ws = (char*)d_ws;
    bf16_t* wtf   = (bf16_t*)(ws);
    bf16_t* q     = (bf16_t*)(ws + 393216);
    bf16_t* kmat  = (bf16_t*)(ws + 17170432);
    bf16_t* v     = (bf16_t*)(ws + 33947648);
    float*  lpart = (float*) (ws + 50724864);
    float*  wpart = (float*) (ws + 50987008);

    wt_kernel<<<dim3(96), dim3(256), 0, stream>>>(Wq, Wk, Wv, wtf);
    proj_kernel<<<dim3(256, 3), dim3(256), 0, stream>>>(x, wtf, bq, bk, bv, q, kmat, v);
    attn_pass<1><<<dim3(512), dim3(256), 0, stream>>>(q, kmat, lpart, wpart);
    attn_pass<2><<<dim3(512), dim3(256), 0, stream>>>(q, kmat, lpart, wpart);
    gemv_kernel<<<dim3(16), dim3(1024), 0, stream>>>(wpart, v, out);
}

// Round 6
// 221.750 us; speedup vs baseline: 3.2472x; 1.0187x over previous
//
#include <hip/hip_runtime.h>
#include <hip/hip_bf16.h>

typedef __bf16 bf16_t;
typedef bf16_t bf16x8 __attribute__((ext_vector_type(8)));
typedef float  f32x4  __attribute__((ext_vector_type(4)));

constexpr int S = 2048, D = 256;

// ---------------- ws layout (bytes) ----------------
// wtf   : [3][16 nt][8 ks][64 lane][8] bf16 (frag-major W^T) @ 0        (393216)
// q     : frag layout [B][128 qb][8 ks][64 lane][8] bf16     @ 393216   (16777216)
// k     : frag layout [B][128 kb][8 ks][64 lane][8] bf16     @ 17170432 (16777216)
// v     : plain [B][S][D] bf16                               @ 33947648 (16777216)
// lpart : [4 kh][16 b][2048] f32                             @ 50724864 (524288)
// wpart : [8 qt][16 b][2048] f32                             @ 51249152 (1048576)
// gpart : [8 ks][16 b][256] f32                              @ 52297728 (131072)
// total : 52428800 (50 MB)

__device__ __forceinline__ float fast_exp2(float x) {
    return __builtin_amdgcn_exp2f(x);
}

// Kernel 1: weights -> bf16 fragment-major layout.
__global__ void wt_kernel(const float* __restrict__ Wq, const float* __restrict__ Wk,
                          const float* __restrict__ Wv, bf16_t* __restrict__ wtf) {
    int idx = blockIdx.x * 256 + threadIdx.x;   // [0, 24576)
    int w    = idx >> 13;
    int rem  = idx & 8191;
    int nt   = rem >> 9;
    int rem2 = rem & 511;
    int ks   = rem2 >> 6;
    int lane = rem2 & 63;
    int lm = lane & 15, lg = lane >> 4;
    const float* Wsrc = (w == 0) ? Wq : (w == 1) ? Wk : Wv;
    int col = nt * 16 + lm, krow = ks * 32 + lg * 8;
    bf16x8 o;
#pragma unroll
    for (int j = 0; j < 8; j++) o[j] = (bf16_t)Wsrc[(krow + j) * 256 + col];
    *(bf16x8*)(wtf + (size_t)idx * 8) = o;
}

// Kernel 2: QKV projection. grid (256, 3), 256 thr (4 waves), 32 rows/wave.
// Epilogue: C-tile -> wave-private LDS (b16 writes) -> row-major bf16x8 reads
// -> vectorized 16B global stores (frag-major for q/k, row-major for v).
__global__ __launch_bounds__(256) void proj_kernel(
    const float* __restrict__ x, const bf16_t* __restrict__ wtf,
    const float* __restrict__ bq, const float* __restrict__ bk, const float* __restrict__ bv,
    bf16_t* __restrict__ qo, bf16_t* __restrict__ ko, bf16_t* __restrict__ vo) {
    __shared__ float xs[2][128 * 36];
    int w    = blockIdx.y;
    int tid  = threadIdx.x;
    int wave = tid >> 6, lane = tid & 63, lm = lane & 15, lg = lane >> 4;
    int m0   = blockIdx.x * 128;
    const bf16_t* wb   = wtf + w * 65536;
    const float*  bias = (w == 0) ? bq : (w == 1) ? bk : bv;

    f32x4 acc[2][16];
#pragma unroll
    for (int s = 0; s < 2; s++)
#pragma unroll
        for (int nt = 0; nt < 16; nt++) acc[s][nt] = f32x4{0.f, 0.f, 0.f, 0.f};

    float4 stg[4];
#pragma unroll
    for (int u = 0; u < 4; u++) {
        int f = u * 256 + tid, row = f >> 3, c4 = f & 7;
        stg[u] = *(const float4*)(x + (size_t)(m0 + row) * 256 + c4 * 4);
    }

    for (int ks = 0; ks < 8; ks++) {
        int p = ks & 1;
#pragma unroll
        for (int u = 0; u < 4; u++) {
            int f = u * 256 + tid, row = f >> 3, c4 = f & 7;
            *(float4*)&xs[p][row * 36 + c4 * 4] = stg[u];
        }
        if (ks < 7) {
#pragma unroll
            for (int u = 0; u < 4; u++) {
                int f = u * 256 + tid, row = f >> 3, c4 = f & 7;
                stg[u] = *(const float4*)(x + (size_t)(m0 + row) * 256 + (ks + 1) * 32 + c4 * 4);
            }
        }
        __syncthreads();
        bf16x8 af[2];
#pragma unroll
        for (int s = 0; s < 2; s++) {
            const float* sp = &xs[p][(wave * 32 + s * 16 + lm) * 36 + lg * 8];
            float4 h0 = *(const float4*)sp;
            float4 h1 = *(const float4*)(sp + 4);
            af[s][0] = (bf16_t)h0.x; af[s][1] = (bf16_t)h0.y;
            af[s][2] = (bf16_t)h0.z; af[s][3] = (bf16_t)h0.w;
            af[s][4] = (bf16_t)h1.x; af[s][5] = (bf16_t)h1.y;
            af[s][6] = (bf16_t)h1.z; af[s][7] = (bf16_t)h1.w;
        }
#pragma unroll
        for (int nt = 0; nt < 16; nt++) {
            bf16x8 bfr = *(const bf16x8*)(wb + (size_t)(nt * 8 + ks) * 512 + lane * 8);
            acc[0][nt] = __builtin_amdgcn_mfma_f32_16x16x32_bf16(af[0], bfr, acc[0][nt], 0, 0, 0);
            acc[1][nt] = __builtin_amdgcn_mfma_f32_16x16x32_bf16(af[1], bfr, acc[1][nt], 0, 0, 0);
        }
    }

    // ---- Epilogue: LDS transpose, vectorized stores ----
    __syncthreads();                         // all waves done reading xs
    // wave-private bf16 buffer: 16 rows x 280 stride (560B, 16B-aligned rows)
    bf16_t* sb = ((bf16_t*)&xs[0][0]) + wave * 4480;
    int bglob = m0 >> 11;
#pragma unroll
    for (int s = 0; s < 2; s++) {
        // write C set s: row = lg*4+r, col = nt*16+lm
#pragma unroll
        for (int nt = 0; nt < 16; nt++) {
            int col = nt * 16 + lm;
            float bval = bias[col];
#pragma unroll
            for (int r = 0; r < 4; r++)
                sb[(lg * 4 + r) * 280 + col] = (bf16_t)(acc[s][nt][r] + bval);
        }
        // read row-major (wave-private; DS pipe is in-order per wave)
        if (w == 2) {
            int ssrow = (m0 & 2047) + wave * 32 + s * 16 + lm;
#pragma unroll
            for (int ks = 0; ks < 8; ks++) {
                bf16x8 v8 = *(const bf16x8*)&sb[lm * 280 + ks * 32 + lg * 8];
                *(bf16x8*)(vo + ((size_t)(bglob * 2048 + ssrow)) * 256 + ks * 32 + lg * 8) = v8;
            }
        } else {
            bf16_t* dst = (w == 0) ? qo : ko;
            int qb = ((m0 & 2047) >> 4) + wave * 2 + s;
#pragma unroll
            for (int ks = 0; ks < 8; ks++) {
                bf16x8 v8 = *(const bf16x8*)&sb[lm * 280 + ks * 32 + lg * 8];
                *(bf16x8*)(dst + ((size_t)((bglob * 128 + qb) * 8 + ks)) * 512 + lane * 8) = v8;
            }
        }
    }
}

// Kernels 3/4: QK^T passes. grid 512 = (16 b x 8 qt(256 rows) x 4 kh(512 keys)),
// 512 threads (8 waves). Wave owns 32 q-rows (A-frags in regs); 32-key K tiles
// staged to LDS (dbuf), shared by 8 waves -> LDS ops per MFMA halved vs R5.
// PASS=1: row-sums l -> lpart.  PASS=2: w_k = sum_q p/l -> wpart.
template <int PASS>
__global__ __launch_bounds__(512) void attn_pass(
    const bf16_t* __restrict__ q, const bf16_t* __restrict__ kmat,
    float* __restrict__ lpart, float* __restrict__ wpart) {
    __shared__ bf16_t kst[2][8192];          // 2 x 16 KB
    __shared__ float  wacc[8][512];          // PASS 2 only

    int tid  = threadIdx.x;
    int wave = tid >> 6, lane = tid & 63, lm = lane & 15, lg = lane >> 4;
    int i  = blockIdx.x;
    int b  = ((i & 7) << 1) | ((i >> 8) & 1);   // XCD-aware: 2 batches per XCD
    int qt = (i >> 3) & 7;
    int kh = (i >> 6) & 3;

    bf16x8 af[2][8];
#pragma unroll
    for (int s = 0; s < 2; s++) {
        const bf16_t* qb = q + ((size_t)((b * 128 + qt * 16 + wave * 2 + s) * 8)) * 512;
#pragma unroll
        for (int ks = 0; ks < 8; ks++)
            af[s][ks] = *(const bf16x8*)(qb + ks * 512 + lane * 8);
    }

    float rinv[2][4];
    if (PASS == 2) {
#pragma unroll
        for (int s = 0; s < 2; s++)
#pragma unroll
            for (int r = 0; r < 4; r++) {
                int row = qt * 256 + wave * 32 + s * 16 + lg * 4 + r;
                float l = 0.f;
#pragma unroll
                for (int k2 = 0; k2 < 4; k2++)
                    l += lpart[(size_t)(k2 * 16 + b) * 2048 + row];
                rinv[s][r] = 1.0f / l;
            }
    }

    float lsum[2][4];
#pragma unroll
    for (int s = 0; s < 2; s++)
#pragma unroll
        for (int r = 0; r < 4; r++) lsum[s][r] = 0.f;

    constexpr float SCL = 0.0625f * 1.44269504f;
    const bf16_t* kb_base = kmat + (size_t)(b * 128 + kh * 32) * 4096;

    bf16x8 stg[2];
#pragma unroll
    for (int u = 0; u < 2; u++)
        stg[u] = *(const bf16x8*)(kb_base + (size_t)(u * 512 + tid) * 8);

    for (int t = 0; t < 16; t++) {
        int p = t & 1;
#pragma unroll
        for (int u = 0; u < 2; u++)
            *(bf16x8*)&kst[p][(u * 512 + tid) * 8] = stg[u];
        if (t < 15) {
#pragma unroll
            for (int u = 0; u < 2; u++)
                stg[u] = *(const bf16x8*)(kb_base + (size_t)(t + 1) * 8192 + (u * 512 + tid) * 8);
        }
        __syncthreads();

        f32x4 sacc[2][2];
#pragma unroll
        for (int s = 0; s < 2; s++)
#pragma unroll
            for (int kb = 0; kb < 2; kb++) sacc[s][kb] = f32x4{0.f, 0.f, 0.f, 0.f};
#pragma unroll
        for (int ks = 0; ks < 8; ks++) {
#pragma unroll
            for (int kb = 0; kb < 2; kb++) {
                bf16x8 bfr = *(const bf16x8*)&kst[p][(kb * 8 + ks) * 512 + lane * 8];
                sacc[0][kb] = __builtin_amdgcn_mfma_f32_16x16x32_bf16(af[0][ks], bfr, sacc[0][kb], 0, 0, 0);
                sacc[1][kb] = __builtin_amdgcn_mfma_f32_16x16x32_bf16(af[1][ks], bfr, sacc[1][kb], 0, 0, 0);
            }
        }

        if (PASS == 1) {
#pragma unroll
            for (int s = 0; s < 2; s++)
#pragma unroll
                for (int kb = 0; kb < 2; kb++)
#pragma unroll
                    for (int r = 0; r < 4; r++)
                        lsum[s][r] += fast_exp2(sacc[s][kb][r] * SCL);
        } else {
            float wv[2] = {0.f, 0.f};
#pragma unroll
            for (int s = 0; s < 2; s++)
#pragma unroll
                for (int kb = 0; kb < 2; kb++)
#pragma unroll
                    for (int r = 0; r < 4; r++)
                        wv[kb] += fast_exp2(sacc[s][kb][r] * SCL) * rinv[s][r];
#pragma unroll
            for (int kb = 0; kb < 2; kb++) {
                float vsum = wv[kb];
                vsum += __shfl_xor(vsum, 16);
                vsum += __shfl_xor(vsum, 32);
                if (lg == 0) wacc[wave][t * 32 + kb * 16 + lm] = vsum;
            }
        }
    }

    if (PASS == 1) {
#pragma unroll
        for (int s = 0; s < 2; s++)
#pragma unroll
            for (int r = 0; r < 4; r++) {
                float v2 = lsum[s][r];
                v2 += __shfl_xor(v2, 1);
                v2 += __shfl_xor(v2, 2);
                v2 += __shfl_xor(v2, 4);
                v2 += __shfl_xor(v2, 8);
                if (lm == 0) {
                    int row = qt * 256 + wave * 32 + s * 16 + lg * 4 + r;
                    lpart[(size_t)(kh * 16 + b) * 2048 + row] = v2;
                }
            }
    } else {
        __syncthreads();
        float sum = 0.f;
#pragma unroll
        for (int w2 = 0; w2 < 8; w2++) sum += wacc[w2][tid];
        wpart[(size_t)(qt * 16 + b) * 2048 + kh * 512 + tid] = sum;
    }
}

// Kernel 5: gpart[kseg,b,d] = sum over 256 keys of w_k V[b,k,d]. grid 128.
__global__ __launch_bounds__(256) void gemv_kernel(
    const float* __restrict__ wpart, const bf16_t* __restrict__ v,
    float* __restrict__ gpart) {
    __shared__ float ldsw[256];
    int b = blockIdx.x >> 3, kseg = blockIdx.x & 7, tid = threadIdx.x;
    int key = kseg * 256 + tid;
    float s = 0.f;
#pragma unroll
    for (int qt = 0; qt < 8; qt++) s += wpart[(size_t)(qt * 16 + b) * 2048 + key];
    ldsw[tid] = s;
    __syncthreads();
    const bf16_t* vb = v + ((size_t)b * 2048 + kseg * 256) * 256;
    float acc = 0.f;
#pragma unroll 4
    for (int t = 0; t < 256; t++) acc += ldsw[t] * (float)vb[(size_t)t * 256 + tid];
    gpart[(size_t)(kseg * 16 + b) * 256 + tid] = acc;
}

// Kernel 6: out[b,d] = sum over 8 ksegs. grid 16 x 256.
__global__ void reduce_kernel(const float* __restrict__ gpart, float* __restrict__ out) {
    int b = blockIdx.x, d = threadIdx.x;
    float t = 0.f;
#pragma unroll
    for (int ks = 0; ks < 8; ks++) t += gpart[(size_t)(ks * 16 + b) * 256 + d];
    out[b * 256 + d] = t;
}

extern "C" void kernel_launch(void* const* d_in, const int* in_sizes, int n_in,
                              void* d_out, int out_size, void* d_ws, size_t ws_size,
                              hipStream_t stream) {
    const float* x  = (const float*)d_in[0];
    const float* Wq = (const float*)d_in[1];
    const float* bq = (const float*)d_in[2];
    const float* Wk = (const float*)d_in[3];
    const float* bk = (const float*)d_in[4];
    const float* Wv = (const float*)d_in[5];
    const float* bv = (const float*)d_in[6];
    float* out = (float*)d_out;

    char* ws = (char*)d_ws;
    bf16_t* wtf   = (bf16_t*)(ws);
    bf16_t* q     = (bf16_t*)(ws + 393216);
    bf16_t* kmat  = (bf16_t*)(ws + 17170432);
    bf16_t* v     = (bf16_t*)(ws + 33947648);
    float*  lpart = (float*) (ws + 50724864);
    float*  wpart = (float*) (ws + 51249152);
    float*  gpart = (float*) (ws + 52297728);

    wt_kernel<<<dim3(96), dim3(256), 0, stream>>>(Wq, Wk, Wv, wtf);
    proj_kernel<<<dim3(256, 3), dim3(256), 0, stream>>>(x, wtf, bq, bk, bv, q, kmat, v);
    attn_pass<1><<<dim3(512), dim3(512), 0, stream>>>(q, kmat, lpart, wpart);
    attn_pass<2><<<dim3(512), dim3(512), 0, stream>>>(q, kmat, lpart, wpart);
    gemv_kernel<<<dim3(128), dim3(256), 0, stream>>>(wpart, v, gpart);
    reduce_kernel<<<dim3(16), dim3(256), 0, stream>>>(gpart, out);
}

// Round 7
// 199.594 us; speedup vs baseline: 3.6077x; 1.1110x over previous
//
#include <hip/hip_runtime.h>
#include <hip/hip_bf16.h>

typedef __bf16 bf16_t;
typedef bf16_t bf16x8 __attribute__((ext_vector_type(8)));
typedef float  f32x4  __attribute__((ext_vector_type(4)));

constexpr int S = 2048, D = 256;

// ---------------- ws layout (bytes) ----------------
// wtf   : [2][16 nt][8 ks][64 lane][8] bf16 (frag W^T q,k)  @ 0        (262144)
// q     : frag layout [B][128 qb][8 ks][64 lane][8] bf16    @ 262144   (16777216)
// k     : frag layout [B][128 kb][8 ks][64 lane][8] bf16    @ 17039360 (16777216)
// lpart : [4 kh][16 b][2048] f32                            @ 33816576 (524288)
// wpart : [8 qt][16 b][2048] f32                            @ 34340864 (1048576)
// gpart : [16 kseg][16 b][256] f32                          @ 35389440 (262144)
// total : 35651584 (~35.7 MB).  V is NEVER materialized:
//   out = (sum_k w_k x_k) @ Wv + 2048*bv   (sum_k w_k == #queries exactly)

__device__ __forceinline__ float fast_exp2(float x) {
    return __builtin_amdgcn_exp2f(x);
}

// Kernel 1: Wq/Wk -> bf16 fragment-major. 16384 elements-of-8.
__global__ void wt_kernel(const float* __restrict__ Wq, const float* __restrict__ Wk,
                          bf16_t* __restrict__ wtf) {
    int idx = blockIdx.x * 256 + threadIdx.x;   // [0, 16384)
    int w    = idx >> 13;
    int rem  = idx & 8191;
    int nt   = rem >> 9;
    int rem2 = rem & 511;
    int ks   = rem2 >> 6;
    int lane = rem2 & 63;
    int lm = lane & 15, lg = lane >> 4;
    const float* Wsrc = (w == 0) ? Wq : Wk;
    int col = nt * 16 + lm, krow = ks * 32 + lg * 8;
    bf16x8 o;
#pragma unroll
    for (int j = 0; j < 8; j++) o[j] = (bf16_t)Wsrc[(krow + j) * 256 + col];
    *(bf16x8*)(wtf + (size_t)idx * 8) = o;
}

// Kernel 2: Q/K projection. grid (256, 2), 256 thr (4 waves), 32 rows/wave.
// Barrier-free: A-frags direct from global x (4 lanes/row read 128B contig),
// B-frags contiguous 1KB from wtf. Epilogue: wave-private LDS transpose ->
// frag-major 16B stores.
__global__ __launch_bounds__(256) void proj_kernel(
    const float* __restrict__ x, const bf16_t* __restrict__ wtf,
    const float* __restrict__ bq, const float* __restrict__ bk,
    bf16_t* __restrict__ qo, bf16_t* __restrict__ ko) {
    __shared__ bf16_t sb_all[4][4480];        // 16 rows x 280 stride per wave
    int w    = blockIdx.y;
    int tid  = threadIdx.x;
    int wave = tid >> 6, lane = tid & 63, lm = lane & 15, lg = lane >> 4;
    int m0   = blockIdx.x * 128;
    const bf16_t* wb   = wtf + w * 65536;
    const float*  bias = (w == 0) ? bq : bk;

    f32x4 acc[2][16];
#pragma unroll
    for (int s = 0; s < 2; s++)
#pragma unroll
        for (int nt = 0; nt < 16; nt++) acc[s][nt] = f32x4{0.f, 0.f, 0.f, 0.f};

    const float* xr0 = x + (size_t)(m0 + wave * 32 + lm) * 256 + lg * 8;
    const float* xr1 = xr0 + 16 * 256;

    for (int ks = 0; ks < 8; ks++) {
        bf16x8 af[2];
        {
            float4 a0 = *(const float4*)(xr0 + ks * 32);
            float4 a1 = *(const float4*)(xr0 + ks * 32 + 4);
            float4 b0 = *(const float4*)(xr1 + ks * 32);
            float4 b1 = *(const float4*)(xr1 + ks * 32 + 4);
            af[0][0] = (bf16_t)a0.x; af[0][1] = (bf16_t)a0.y;
            af[0][2] = (bf16_t)a0.z; af[0][3] = (bf16_t)a0.w;
            af[0][4] = (bf16_t)a1.x; af[0][5] = (bf16_t)a1.y;
            af[0][6] = (bf16_t)a1.z; af[0][7] = (bf16_t)a1.w;
            af[1][0] = (bf16_t)b0.x; af[1][1] = (bf16_t)b0.y;
            af[1][2] = (bf16_t)b0.z; af[1][3] = (bf16_t)b0.w;
            af[1][4] = (bf16_t)b1.x; af[1][5] = (bf16_t)b1.y;
            af[1][6] = (bf16_t)b1.z; af[1][7] = (bf16_t)b1.w;
        }
#pragma unroll
        for (int nt = 0; nt < 16; nt++) {
            bf16x8 bfr = *(const bf16x8*)(wb + (size_t)(nt * 8 + ks) * 512 + lane * 8);
            acc[0][nt] = __builtin_amdgcn_mfma_f32_16x16x32_bf16(af[0], bfr, acc[0][nt], 0, 0, 0);
            acc[1][nt] = __builtin_amdgcn_mfma_f32_16x16x32_bf16(af[1], bfr, acc[1][nt], 0, 0, 0);
        }
    }

    // Epilogue (wave-private, no barriers; DS pipe is in-order per wave).
    bf16_t* sb = sb_all[wave];
    int bglob = m0 >> 11;
    bf16_t* dst = (w == 0) ? qo : ko;
#pragma unroll
    for (int s = 0; s < 2; s++) {
#pragma unroll
        for (int nt = 0; nt < 16; nt++) {
            int col = nt * 16 + lm;
            float bval = bias[col];
#pragma unroll
            for (int r = 0; r < 4; r++)
                sb[(lg * 4 + r) * 280 + col] = (bf16_t)(acc[s][nt][r] + bval);
        }
        int qb = ((m0 & 2047) >> 4) + wave * 2 + s;
#pragma unroll
        for (int ks = 0; ks < 8; ks++) {
            bf16x8 v8 = *(const bf16x8*)&sb[lm * 280 + ks * 32 + lg * 8];
            *(bf16x8*)(dst + ((size_t)((bglob * 128 + qb) * 8 + ks)) * 512 + lane * 8) = v8;
        }
    }
}

// Kernels 3/4: QK^T passes. grid 512 = (16 b x 8 qt(256 rows) x 4 kh(512 keys)),
// 512 thr (8 waves). Wave owns 32 q-rows (A-frags in regs); 64-key K tiles
// staged to LDS (2x32KB dbuf), shared by 8 waves; 8 barriers per kernel body.
// PASS=1: row-sums l -> lpart.  PASS=2: w_k = sum_q p/l -> wpart.
template <int PASS>
__global__ __launch_bounds__(512) void attn_pass(
    const bf16_t* __restrict__ q, const bf16_t* __restrict__ kmat,
    float* __restrict__ lpart, float* __restrict__ wpart) {
    __shared__ bf16_t kst[2][16384];          // 2 x 32 KB
    __shared__ bf16_t wacc[8][512];           // PASS 2 only (bf16: fits 2 blk/CU)

    int tid  = threadIdx.x;
    int wave = tid >> 6, lane = tid & 63, lm = lane & 15, lg = lane >> 4;
    int i  = blockIdx.x;
    int b  = ((i & 7) << 1) | ((i >> 8) & 1);   // XCD-aware: 2 batches per XCD
    int qt = (i >> 3) & 7;
    int kh = (i >> 6) & 3;

    bf16x8 af[2][8];
#pragma unroll
    for (int s = 0; s < 2; s++) {
        const bf16_t* qb = q + ((size_t)((b * 128 + qt * 16 + wave * 2 + s) * 8)) * 512;
#pragma unroll
        for (int ks = 0; ks < 8; ks++)
            af[s][ks] = *(const bf16x8*)(qb + ks * 512 + lane * 8);
    }

    float rinv[2][4];
    if (PASS == 2) {
#pragma unroll
        for (int s = 0; s < 2; s++)
#pragma unroll
            for (int r = 0; r < 4; r++) {
                int row = qt * 256 + wave * 32 + s * 16 + lg * 4 + r;
                float l = 0.f;
#pragma unroll
                for (int k2 = 0; k2 < 4; k2++)
                    l += lpart[(size_t)(k2 * 16 + b) * 2048 + row];
                rinv[s][r] = 1.0f / l;
            }
    }

    float lsum[2][4];
#pragma unroll
    for (int s = 0; s < 2; s++)
#pragma unroll
        for (int r = 0; r < 4; r++) lsum[s][r] = 0.f;

    constexpr float SCL = 0.0625f * 1.44269504f;
    const bf16_t* kb_base = kmat + (size_t)(b * 128 + kh * 32) * 4096;

    bf16x8 stg[4];
#pragma unroll
    for (int u = 0; u < 4; u++)
        stg[u] = *(const bf16x8*)(kb_base + (size_t)(u * 512 + tid) * 8);

    for (int t = 0; t < 8; t++) {
        int p = t & 1;
#pragma unroll
        for (int u = 0; u < 4; u++)
            *(bf16x8*)&kst[p][(u * 512 + tid) * 8] = stg[u];
        if (t < 7) {
#pragma unroll
            for (int u = 0; u < 4; u++)
                stg[u] = *(const bf16x8*)(kb_base + (size_t)(t + 1) * 16384 + (u * 512 + tid) * 8);
        }
        __syncthreads();

        f32x4 sacc[2][4];
#pragma unroll
        for (int s = 0; s < 2; s++)
#pragma unroll
            for (int kb = 0; kb < 4; kb++) sacc[s][kb] = f32x4{0.f, 0.f, 0.f, 0.f};
#pragma unroll
        for (int ks = 0; ks < 8; ks++) {
#pragma unroll
            for (int kb = 0; kb < 4; kb++) {
                bf16x8 bfr = *(const bf16x8*)&kst[p][(kb * 8 + ks) * 512 + lane * 8];
                sacc[0][kb] = __builtin_amdgcn_mfma_f32_16x16x32_bf16(af[0][ks], bfr, sacc[0][kb], 0, 0, 0);
                sacc[1][kb] = __builtin_amdgcn_mfma_f32_16x16x32_bf16(af[1][ks], bfr, sacc[1][kb], 0, 0, 0);
            }
        }

        if (PASS == 1) {
#pragma unroll
            for (int s = 0; s < 2; s++)
#pragma unroll
                for (int kb = 0; kb < 4; kb++)
#pragma unroll
                    for (int r = 0; r < 4; r++)
                        lsum[s][r] += fast_exp2(sacc[s][kb][r] * SCL);
        } else {
            float wv[4] = {0.f, 0.f, 0.f, 0.f};
#pragma unroll
            for (int s = 0; s < 2; s++)
#pragma unroll
                for (int kb = 0; kb < 4; kb++)
#pragma unroll
                    for (int r = 0; r < 4; r++)
                        wv[kb] += fast_exp2(sacc[s][kb][r] * SCL) * rinv[s][r];
#pragma unroll
            for (int kb = 0; kb < 4; kb++) {
                float vsum = wv[kb];
                vsum += __shfl_xor(vsum, 16);
                vsum += __shfl_xor(vsum, 32);
                if (lg == 0) wacc[wave][t * 64 + kb * 16 + lm] = (bf16_t)vsum;
            }
        }
    }

    if (PASS == 1) {
#pragma unroll
        for (int s = 0; s < 2; s++)
#pragma unroll
            for (int r = 0; r < 4; r++) {
                float v2 = lsum[s][r];
                v2 += __shfl_xor(v2, 1);
                v2 += __shfl_xor(v2, 2);
                v2 += __shfl_xor(v2, 4);
                v2 += __shfl_xor(v2, 8);
                if (lm == 0) {
                    int row = qt * 256 + wave * 32 + s * 16 + lg * 4 + r;
                    lpart[(size_t)(kh * 16 + b) * 2048 + row] = v2;
                }
            }
    } else {
        __syncthreads();
        float sum = 0.f;
#pragma unroll
        for (int w2 = 0; w2 < 8; w2++) sum += (float)wacc[w2][tid];
        wpart[(size_t)(qt * 16 + b) * 2048 + kh * 512 + tid] = sum;
    }
}

// Kernel 5: gpart[kseg,b,d] = sum over 128 keys of w_k x[b,k,d] (fp32 x!).
// grid 256 = 16 b x 16 kseg.
__global__ __launch_bounds__(256) void xsum_kernel(
    const float* __restrict__ wpart, const float* __restrict__ x,
    float* __restrict__ gpart) {
    __shared__ float ldsw[128];
    int b = blockIdx.x >> 4, kseg = blockIdx.x & 15, tid = threadIdx.x;
    if (tid < 128) {
        int key = kseg * 128 + tid;
        float s = 0.f;
#pragma unroll
        for (int qt = 0; qt < 8; qt++) s += wpart[(size_t)(qt * 16 + b) * 2048 + key];
        ldsw[tid] = s;
    }
    __syncthreads();
    const float* xb = x + ((size_t)b * 2048 + kseg * 128) * 256;
    float acc = 0.f;
#pragma unroll 8
    for (int t = 0; t < 128; t++) acc += ldsw[t] * xb[(size_t)t * 256 + tid];
    gpart[(size_t)(kseg * 16 + b) * 256 + tid] = acc;
}

// Kernel 6: out[b,d] = (sum_kseg gpart)[b,:] @ Wv[:,d] + 2048*bv[d]. grid 16.
__global__ __launch_bounds__(256) void final_kernel(
    const float* __restrict__ gpart, const float* __restrict__ Wv,
    const float* __restrict__ bv, float* __restrict__ out) {
    __shared__ float yl[256];
    int b = blockIdx.x, tid = threadIdx.x;
    float s = 0.f;
#pragma unroll
    for (int ks = 0; ks < 16; ks++) s += gpart[(size_t)(ks * 16 + b) * 256 + tid];
    yl[tid] = s;
    __syncthreads();
    float acc = 0.f;
#pragma unroll 4
    for (int c = 0; c < 256; c++) acc += yl[c] * Wv[c * 256 + tid];
    out[b * 256 + tid] = acc + 2048.0f * bv[tid];
}

extern "C" void kernel_launch(void* const* d_in, const int* in_sizes, int n_in,
                              void* d_out, int out_size, void* d_ws, size_t ws_size,
                              hipStream_t stream) {
    const float* x  = (const float*)d_in[0];
    const float* Wq = (const float*)d_in[1];
    const float* bq = (const float*)d_in[2];
    const float* Wk = (const float*)d_in[3];
    const float* bk = (const float*)d_in[4];
    const float* Wv = (const float*)d_in[5];
    const float* bv = (const float*)d_in[6];
    float* out = (float*)d_out;

    char* ws = (char*)d_ws;
    bf16_t* wtf   = (bf16_t*)(ws);
    bf16_t* q     = (bf16_t*)(ws + 262144);
    bf16_t* kmat  = (bf16_t*)(ws + 17039360);
    float*  lpart = (float*) (ws + 33816576);
    float*  wpart = (float*) (ws + 34340864);
    float*  gpart = (float*) (ws + 35389440);

    wt_kernel<<<dim3(64), dim3(256), 0, stream>>>(Wq, Wk, wtf);
    proj_kernel<<<dim3(256, 2), dim3(256), 0, stream>>>(x, wtf, bq, bk, q, kmat);
    attn_pass<1><<<dim3(512), dim3(512), 0, stream>>>(q, kmat, lpart, wpart);
    attn_pass<2><<<dim3(512), dim3(512), 0, stream>>>(q, kmat, lpart, wpart);
    xsum_kernel<<<dim3(256), dim3(256), 0, stream>>>(wpart, x, gpart);
    final_kernel<<<dim3(16), dim3(256), 0, stream>>>(gpart, Wv, bv, out);
}

// Round 8
// 191.299 us; speedup vs baseline: 3.7641x; 1.0434x over previous
//
#include <hip/hip_runtime.h>
#include <hip/hip_bf16.h>

typedef __bf16 bf16_t;
typedef bf16_t bf16x8 __attribute__((ext_vector_type(8)));
typedef float  f32x4  __attribute__((ext_vector_type(4)));

constexpr int S = 2048, D = 256;

// ---------------- ws layout (bytes) ----------------
// wtf   : [2][16 nt][8 ks][64 lane][8] bf16 (frag W^T q,k)  @ 0        (262144)
// q     : frag layout [B][128 qb][8 ks][64 lane][8] bf16    @ 262144   (16777216)
// k     : frag layout [B][128 kb][8 ks][64 lane][8] bf16    @ 17039360 (16777216)
// lpart : [4 kh][16 b][2048] f32                            @ 33816576 (524288)
// wpart : [4 qt][16 b][2048] f32                            @ 34340864 (524288)
// gpart : [16 kseg][16 b][256] f32                          @ 34865152 (262144)
// total : 35127296 (~35.1 MB).  V is NEVER materialized:
//   out = (sum_k w_k x_k) @ Wv + 2048*bv   (sum_k w_k == #queries exactly)

__device__ __forceinline__ float fast_exp2(float x) {
    return __builtin_amdgcn_exp2f(x);
}

// Kernel 1: Wq/Wk -> bf16 fragment-major.
__global__ void wt_kernel(const float* __restrict__ Wq, const float* __restrict__ Wk,
                          bf16_t* __restrict__ wtf) {
    int idx = blockIdx.x * 256 + threadIdx.x;   // [0, 16384)
    int w    = idx >> 13;
    int rem  = idx & 8191;
    int nt   = rem >> 9;
    int rem2 = rem & 511;
    int ks   = rem2 >> 6;
    int lane = rem2 & 63;
    int lm = lane & 15, lg = lane >> 4;
    const float* Wsrc = (w == 0) ? Wq : Wk;
    int col = nt * 16 + lm, krow = ks * 32 + lg * 8;
    bf16x8 o;
#pragma unroll
    for (int j = 0; j < 8; j++) o[j] = (bf16_t)Wsrc[(krow + j) * 256 + col];
    *(bf16x8*)(wtf + (size_t)idx * 8) = o;
}

// Kernel 2: Q/K projection. grid (256, 2), 256 thr (4 waves), 32 rows/wave.
// Barrier-free; epilogue via wave-private LDS transpose -> frag-major stores.
__global__ __launch_bounds__(256) void proj_kernel(
    const float* __restrict__ x, const bf16_t* __restrict__ wtf,
    const float* __restrict__ bq, const float* __restrict__ bk,
    bf16_t* __restrict__ qo, bf16_t* __restrict__ ko) {
    __shared__ bf16_t sb_all[4][4480];
    int w    = blockIdx.y;
    int tid  = threadIdx.x;
    int wave = tid >> 6, lane = tid & 63, lm = lane & 15, lg = lane >> 4;
    int m0   = blockIdx.x * 128;
    const bf16_t* wb   = wtf + w * 65536;
    const float*  bias = (w == 0) ? bq : bk;

    f32x4 acc[2][16];
#pragma unroll
    for (int s = 0; s < 2; s++)
#pragma unroll
        for (int nt = 0; nt < 16; nt++) acc[s][nt] = f32x4{0.f, 0.f, 0.f, 0.f};

    const float* xr0 = x + (size_t)(m0 + wave * 32 + lm) * 256 + lg * 8;
    const float* xr1 = xr0 + 16 * 256;

    for (int ks = 0; ks < 8; ks++) {
        bf16x8 af[2];
        {
            float4 a0 = *(const float4*)(xr0 + ks * 32);
            float4 a1 = *(const float4*)(xr0 + ks * 32 + 4);
            float4 b0 = *(const float4*)(xr1 + ks * 32);
            float4 b1 = *(const float4*)(xr1 + ks * 32 + 4);
            af[0][0] = (bf16_t)a0.x; af[0][1] = (bf16_t)a0.y;
            af[0][2] = (bf16_t)a0.z; af[0][3] = (bf16_t)a0.w;
            af[0][4] = (bf16_t)a1.x; af[0][5] = (bf16_t)a1.y;
            af[0][6] = (bf16_t)a1.z; af[0][7] = (bf16_t)a1.w;
            af[1][0] = (bf16_t)b0.x; af[1][1] = (bf16_t)b0.y;
            af[1][2] = (bf16_t)b0.z; af[1][3] = (bf16_t)b0.w;
            af[1][4] = (bf16_t)b1.x; af[1][5] = (bf16_t)b1.y;
            af[1][6] = (bf16_t)b1.z; af[1][7] = (bf16_t)b1.w;
        }
#pragma unroll
        for (int nt = 0; nt < 16; nt++) {
            bf16x8 bfr = *(const bf16x8*)(wb + (size_t)(nt * 8 + ks) * 512 + lane * 8);
            acc[0][nt] = __builtin_amdgcn_mfma_f32_16x16x32_bf16(af[0], bfr, acc[0][nt], 0, 0, 0);
            acc[1][nt] = __builtin_amdgcn_mfma_f32_16x16x32_bf16(af[1], bfr, acc[1][nt], 0, 0, 0);
        }
    }

    bf16_t* sb = sb_all[wave];
    int bglob = m0 >> 11;
    bf16_t* dst = (w == 0) ? qo : ko;
#pragma unroll
    for (int s = 0; s < 2; s++) {
#pragma unroll
        for (int nt = 0; nt < 16; nt++) {
            int col = nt * 16 + lm;
            float bval = bias[col];
#pragma unroll
            for (int r = 0; r < 4; r++)
                sb[(lg * 4 + r) * 280 + col] = (bf16_t)(acc[s][nt][r] + bval);
        }
        int qb = ((m0 & 2047) >> 4) + wave * 2 + s;
#pragma unroll
        for (int ks = 0; ks < 8; ks++) {
            bf16x8 v8 = *(const bf16x8*)&sb[lm * 280 + ks * 32 + lg * 8];
            *(bf16x8*)(dst + ((size_t)((bglob * 128 + qb) * 8 + ks)) * 512 + lane * 8) = v8;
        }
    }
}

// Kernels 3/4: QK^T passes. grid 256 = (16 b x 4 qt(512 rows) x 4 kh(512 keys)),
// 512 thr (8 waves). Wave owns 64 q-rows (4 A-sets in regs -> B-frag reuse 4);
// 64-key K tiles staged to LDS (2x32KB dbuf), shared by 8 waves.
// Per-CU per-tile: MFMA ~4966 cyc vs LDS ~2340 cyc -> MFMA-bound.
// PASS=1: row-sums l -> lpart.  PASS=2: w_k = sum_q p/l -> wpart.
template <int PASS>
__global__ __launch_bounds__(512, 2) void attn_pass(
    const bf16_t* __restrict__ q, const bf16_t* __restrict__ kmat,
    float* __restrict__ lpart, float* __restrict__ wpart) {
    __shared__ bf16_t kst[2][16384];          // 2 x 32 KB
    __shared__ bf16_t wacc[8][512];           // PASS 2 only

    int tid  = threadIdx.x;
    int wave = tid >> 6, lane = tid & 63, lm = lane & 15, lg = lane >> 4;
    int i    = blockIdx.x;                    // 256 blocks
    int idx2 = i >> 3;                        // 0..31
    int qt   = idx2 & 3;
    int kh   = (idx2 >> 2) & 3;
    int b    = (i & 7) * 2 + (idx2 >> 4);     // XCD-aware: 2 batches per XCD

    // A-frags: 4 sets x 16 q-rows = 64 q-rows per wave (128 VGPRs).
    bf16x8 af[4][8];
#pragma unroll
    for (int s = 0; s < 4; s++) {
        const bf16_t* qb = q + ((size_t)((b * 128 + qt * 32 + wave * 4 + s) * 8)) * 512;
#pragma unroll
        for (int ks = 0; ks < 8; ks++)
            af[s][ks] = *(const bf16x8*)(qb + ks * 512 + lane * 8);
    }

    float rinv[4][4];
    if (PASS == 2) {
#pragma unroll
        for (int s = 0; s < 4; s++)
#pragma unroll
            for (int r = 0; r < 4; r++) {
                int row = qt * 512 + wave * 64 + s * 16 + lg * 4 + r;
                float l = 0.f;
#pragma unroll
                for (int k2 = 0; k2 < 4; k2++)
                    l += lpart[(size_t)(k2 * 16 + b) * 2048 + row];
                rinv[s][r] = 1.0f / l;
            }
    }

    float lsum[4][4];
#pragma unroll
    for (int s = 0; s < 4; s++)
#pragma unroll
        for (int r = 0; r < 4; r++) lsum[s][r] = 0.f;

    constexpr float SCL = 0.0625f * 1.44269504f;
    const bf16_t* kb_base = kmat + (size_t)(b * 128 + kh * 32) * 4096;

    bf16x8 stg[4];
#pragma unroll
    for (int u = 0; u < 4; u++)
        stg[u] = *(const bf16x8*)(kb_base + (size_t)(u * 512 + tid) * 8);

    for (int t = 0; t < 8; t++) {
        int p = t & 1;
#pragma unroll
        for (int u = 0; u < 4; u++)
            *(bf16x8*)&kst[p][(u * 512 + tid) * 8] = stg[u];
        if (t < 7) {
#pragma unroll
            for (int u = 0; u < 4; u++)
                stg[u] = *(const bf16x8*)(kb_base + (size_t)(t + 1) * 16384 + (u * 512 + tid) * 8);
        }
        __syncthreads();

        // two kb-pairs of 32 keys each; sacc[4][2] keeps VGPRs ~220 total
#pragma unroll
        for (int h = 0; h < 2; h++) {
            f32x4 sacc[4][2];
#pragma unroll
            for (int s = 0; s < 4; s++) {
                sacc[s][0] = f32x4{0.f, 0.f, 0.f, 0.f};
                sacc[s][1] = f32x4{0.f, 0.f, 0.f, 0.f};
            }
#pragma unroll
            for (int ks = 0; ks < 8; ks++) {
                bf16x8 b0 = *(const bf16x8*)&kst[p][((h * 2 + 0) * 8 + ks) * 512 + lane * 8];
                bf16x8 b1 = *(const bf16x8*)&kst[p][((h * 2 + 1) * 8 + ks) * 512 + lane * 8];
#pragma unroll
                for (int s = 0; s < 4; s++) {
                    sacc[s][0] = __builtin_amdgcn_mfma_f32_16x16x32_bf16(af[s][ks], b0, sacc[s][0], 0, 0, 0);
                    sacc[s][1] = __builtin_amdgcn_mfma_f32_16x16x32_bf16(af[s][ks], b1, sacc[s][1], 0, 0, 0);
                }
            }
            if (PASS == 1) {
#pragma unroll
                for (int s = 0; s < 4; s++)
#pragma unroll
                    for (int j = 0; j < 2; j++)
#pragma unroll
                        for (int r = 0; r < 4; r++)
                            lsum[s][r] += fast_exp2(sacc[s][j][r] * SCL);
            } else {
#pragma unroll
                for (int j = 0; j < 2; j++) {
                    float wv = 0.f;
#pragma unroll
                    for (int s = 0; s < 4; s++)
#pragma unroll
                        for (int r = 0; r < 4; r++)
                            wv += fast_exp2(sacc[s][j][r] * SCL) * rinv[s][r];
                    wv += __shfl_xor(wv, 16);
                    wv += __shfl_xor(wv, 32);
                    if (lg == 0) wacc[wave][t * 64 + (h * 2 + j) * 16 + lm] = (bf16_t)wv;
                }
            }
        }
    }

    if (PASS == 1) {
#pragma unroll
        for (int s = 0; s < 4; s++)
#pragma unroll
            for (int r = 0; r < 4; r++) {
                float v2 = lsum[s][r];
                v2 += __shfl_xor(v2, 1);
                v2 += __shfl_xor(v2, 2);
                v2 += __shfl_xor(v2, 4);
                v2 += __shfl_xor(v2, 8);
                if (lm == 0) {
                    int row = qt * 512 + wave * 64 + s * 16 + lg * 4 + r;
                    lpart[(size_t)(kh * 16 + b) * 2048 + row] = v2;
                }
            }
    } else {
        __syncthreads();
        float sum = 0.f;
#pragma unroll
        for (int w2 = 0; w2 < 8; w2++) sum += (float)wacc[w2][tid];
        wpart[(size_t)(qt * 16 + b) * 2048 + kh * 512 + tid] = sum;
    }
}

// Kernel 5: gpart[kseg,b,d] = sum over 128 keys of w_k x[b,k,d] (fp32 x).
__global__ __launch_bounds__(256) void xsum_kernel(
    const float* __restrict__ wpart, const float* __restrict__ x,
    float* __restrict__ gpart) {
    __shared__ float ldsw[128];
    int b = blockIdx.x >> 4, kseg = blockIdx.x & 15, tid = threadIdx.x;
    if (tid < 128) {
        int key = kseg * 128 + tid;
        float s = 0.f;
#pragma unroll
        for (int qt = 0; qt < 4; qt++) s += wpart[(size_t)(qt * 16 + b) * 2048 + key];
        ldsw[tid] = s;
    }
    __syncthreads();
    const float* xb = x + ((size_t)b * 2048 + kseg * 128) * 256;
    float acc = 0.f;
#pragma unroll 8
    for (int t = 0; t < 128; t++) acc += ldsw[t] * xb[(size_t)t * 256 + tid];
    gpart[(size_t)(kseg * 16 + b) * 256 + tid] = acc;
}

// Kernel 6: out[b,d] = (sum_kseg gpart)[b,:] @ Wv[:,d] + 2048*bv[d].
__global__ __launch_bounds__(256) void final_kernel(
    const float* __restrict__ gpart, const float* __restrict__ Wv,
    const float* __restrict__ bv, float* __restrict__ out) {
    __shared__ float yl[256];
    int b = blockIdx.x, tid = threadIdx.x;
    float s = 0.f;
#pragma unroll
    for (int ks = 0; ks < 16; ks++) s += gpart[(size_t)(ks * 16 + b) * 256 + tid];
    yl[tid] = s;
    __syncthreads();
    float acc = 0.f;
#pragma unroll 4
    for (int c = 0; c < 256; c++) acc += yl[c] * Wv[c * 256 + tid];
    out[b * 256 + tid] = acc + 2048.0f * bv[tid];
}

extern "C" void kernel_launch(void* const* d_in, const int* in_sizes, int n_in,
                              void* d_out, int out_size, void* d_ws, size_t ws_size,
                              hipStream_t stream) {
    const float* x  = (const float*)d_in[0];
    const float* Wq = (const float*)d_in[1];
    const float* bq = (const float*)d_in[2];
    const float* Wk = (const float*)d_in[3];
    const float* bk = (const float*)d_in[4];
    const float* Wv = (const float*)d_in[5];
    const float* bv = (const float*)d_in[6];
    float* out = (float*)d_out;

    char* ws = (char*)d_ws;
    bf16_t* wtf   = (bf16_t*)(ws);
    bf16_t* q     = (bf16_t*)(ws + 262144);
    bf16_t* kmat  = (bf16_t*)(ws + 17039360);
    float*  lpart = (float*) (ws + 33816576);
    float*  wpart = (float*) (ws + 34340864);
    float*  gpart = (float*) (ws + 34865152);

    wt_kernel<<<dim3(64), dim3(256), 0, stream>>>(Wq, Wk, wtf);
    proj_kernel<<<dim3(256, 2), dim3(256), 0, stream>>>(x, wtf, bq, bk, q, kmat);
    attn_pass<1><<<dim3(256), dim3(512), 0, stream>>>(q, kmat, lpart, wpart);
    attn_pass<2><<<dim3(256), dim3(512), 0, stream>>>(q, kmat, lpart, wpart);
    xsum_kernel<<<dim3(256), dim3(256), 0, stream>>>(wpart, x, gpart);
    final_kernel<<<dim3(16), dim3(256), 0, stream>>>(gpart, Wv, bv, out);
}